// Round 11
// baseline (1490.097 us; speedup 1.0000x reference)
//
#include <hip/hip_runtime.h>
#include <stdint.h>
#include <math.h>

#define T_ 4
#define B_ 16
#define C_ 256
#define N_ 1024
#define HD_ 1024
#define HEADS_ 8
#define DH_ 32

typedef float   v2f  __attribute__((ext_vector_type(2)));
typedef float   f4v  __attribute__((ext_vector_type(4)));
typedef uint8_t u8x4 __attribute__((ext_vector_type(4)));

// v_pk_fma_f32 with op_sel broadcasting one 32-bit half of src0 (VGPR) to both
// halves. Two independent IEEE fp32 FMAs; bit-exact per-output chains.
// (Verified numerically correct: rounds 0/6/10, absmax 0.0.)
#define PKL(a, w, x) asm volatile("v_pk_fma_f32 %0, %1, %2, %0 op_sel:[0,0,0] op_sel_hi:[0,1,1]" : "+v"(a) : "v"(w), "v"(x))
#define PKH(a, w, x) asm volatile("v_pk_fma_f32 %0, %1, %2, %0 op_sel:[1,0,0] op_sel_hi:[1,1,1]" : "+v"(a) : "v"(w), "v"(x))

// counted lgkm wait: SAFE because the counted region contains ONLY DS ops
// (ds_* retire in-order in lgkmcnt; no SMEM/flat in the counted region —
// ldstage forced to address_space(1) => global_load => vmcnt only).
template<int N> __device__ __forceinline__ void waitl(){
  asm volatile("s_waitcnt lgkmcnt(%0)" :: "i"(N) : "memory");
  __builtin_amdgcn_sched_barrier(0);       // rule #18 fence
}

// Wp[((k>>1)*(OD/8) + (o+ooff)/8)*16 + (k&1)*8 + (o+ooff)%8] = W[o][k]
// => contiguous 64B per {2 k's} x {8 o's} half-tile.
__global__ __launch_bounds__(256)
void packW(const float* __restrict__ W, float* __restrict__ Wp,
           int K, int OD, int ooff)
{
  int k = blockIdx.x*256 + threadIdx.x;
  int oo = blockIdx.y + ooff;
  Wp[((size_t)(k>>1)*(OD>>3) + (oo>>3))*16 + ((k&1)<<3) + (oo&7)]
      = W[(size_t)blockIdx.y*K + k];
}

__global__ __launch_bounds__(256)
void packBn3(const float* __restrict__ a, const float* __restrict__ b,
             const float* __restrict__ c, float* __restrict__ o)
{
  int i = blockIdx.x*256 + threadIdx.x;            // 0..1023 = [4][256]
  int r = i >> 8, ci = i & 255;
  o[(size_t)r*768 + ci]       = a[i];
  o[(size_t)r*768 + 256 + ci] = b[i];
  o[(size_t)r*768 + 512 + ci] = c[i];
}

template<typename T> struct VecT;
template<> struct VecT<float>  { using t = f4v;  };
template<> struct VecT<uint8_t>{ using t = u8x4; };
__device__ __forceinline__ f4v cvt4(f4v v){ return v; }
__device__ __forceinline__ f4v cvt4(u8x4 u){
  return (f4v){ (float)u[0], (float)u[1], (float)u[2], (float)u[3] };
}

// ---------------------------------------------------------------------------
// Y = W @ X (+bias) -> BN -> LIF, t-loop inside block (LIF state in regs).
// Block 256 thr: o-tile 32 (wave owns 8 o, wave-uniform), n-tile 256 (lane 4n).
// BOTH X and W staged global->reg->LDS per 16-k chunk (verified pattern);
// hot loop is PURE DS: per half (2 k's) 2 contiguous ds_read_b128 (X) + 4
// wave-uniform broadcast ds_read_b128 (W, conflict-free).
// 3-slot register ring, issue-ahead distance 2 halves (~128cy > ~120cy LDS
// latency => waits ~free even single-wave).  ISSUEH(h+3) placed AFTER CH(h)
// so its slot (h mod 3) is already consumed — no WAR clobber; in-flight
// slots {h,h+1,h+2} mod 3 all distinct.  Counted lgkmcnt exact (in-order DS).
// Numeric contract: per output, strictly k-ascending fp32 FMA chain;
// epilogue formula chain identical to all verified rounds (absmax 0.0).
// ---------------------------------------------------------------------------
template<int KDIM,int ODIM,bool HAS_BIAS,int MODE,typename TIn>
__global__ __launch_bounds__(256,3)
void dgemm(const TIn* __restrict__ X, const float* __restrict__ Wp,
           const float* __restrict__ bias, const float* __restrict__ bn,
           const float* __restrict__ resid, void* __restrict__ out, float vth)
{
  using XV = typename VecT<TIn>::t;
  constexpr int NC = KDIM/16;                 // 16-k chunks per t
  __shared__ __align__(16) float Xs[2][16*256];   // 32 KB
  __shared__ __align__(16) float Ws[2][512];      //  4 KB

  const int tid  = threadIdx.x;
  const int lane = tid & 63;
  const int wid  = __builtin_amdgcn_readfirstlane(tid >> 6);
  const int b    = blockIdx.z, n0 = blockIdx.x*256, o0 = blockIdx.y*32;
  const int og0  = o0 >> 3;
  // W-stage decomposition of tid: half wh (0..7), o-group wg (0..3), elem we
  const int wh = tid >> 5, wg = (tid >> 3) & 3, we = tid & 7;

  const uint32_t lxB =
      (uint32_t)(uintptr_t)(__attribute__((address_space(3))) float*)&Xs[0][0]
      + (uint32_t)(lane*16);
  const uint32_t lwB =
      (uint32_t)(uintptr_t)(__attribute__((address_space(3))) float*)&Ws[0][0]
      + (uint32_t)(wid*64);

  v2f acc[8][2], vli[8][2];
#pragma unroll
  for (int i=0;i<8;i++){ vli[i][0]=(v2f){0.f,0.f}; vli[i][1]=(v2f){0.f,0.f}; }

  f4v xb[3][2];      // [h mod 3][k-parity]
  f4v wrg[3][4];     // [h mod 3][{kev o0-3, kev o4-7, kod o0-3, kod o4-7}]
  XV  sreg[4];
  v2f wsreg;

  // stage-register loads for global chunk ch = t*NC + c.
  // Explicit address_space(1) => global_load (vmcnt ONLY — never flat/lgkm),
  // keeping the counted-lgkm region pure-DS.  Issued a full chunk (~1000cy)
  // ahead of the LDS write => covers HBM latency.
  auto ldstage = [&](int ch){
    const int t = ch / NC, c = ch % NC;
    const TIn* Xg = X + ((size_t)(t*B_+b)*KDIM + c*16)*N_ + n0 + lane*4;
#pragma unroll
    for (int r=0;r<4;r++)
      sreg[r] = *(const __attribute__((address_space(1))) XV*)
                  (Xg + (size_t)((tid>>6) + 4*r)*N_);
    wsreg = *(const __attribute__((address_space(1))) v2f*)
        (Wp + ((size_t)(c*8 + wh)*(ODIM>>3) + og0 + wg)*16 + 2*we);
  };

  // issue all 6 DS reads for half h of buffer pb (pb,h compile-time literals)
#define ISSUEH(pb, h) do{                                                      \
    uint32_t lx_ = lxB + (uint32_t)((pb)*16384 + (h)*2048);                    \
    asm volatile("ds_read_b128 %0, %2\n\tds_read_b128 %1, %2 offset:1024"      \
                 : "=v"(xb[(h)%3][0]), "=v"(xb[(h)%3][1]) : "v"(lx_));         \
    uint32_t lw_ = lwB + (uint32_t)((pb)*2048 + (h)*256);                      \
    asm volatile("ds_read_b128 %0, %4\n\tds_read_b128 %1, %4 offset:16\n\t"    \
                 "ds_read_b128 %2, %4 offset:32\n\tds_read_b128 %3, %4 offset:48" \
                 : "=v"(wrg[(h)%3][0]), "=v"(wrg[(h)%3][1]),                   \
                   "=v"(wrg[(h)%3][2]), "=v"(wrg[(h)%3][3]) : "v"(lw_));       \
  }while(0)

  // compute half h: k=2h then k=2h+1; strict ascending-k order per output
#define CH(h) do{                                                              \
    _Pragma("unroll")                                                          \
    for (int e=0;e<2;e++){                                                     \
      v2f xa = __builtin_shufflevector(xb[(h)%3][e], xb[(h)%3][e], 0,1);       \
      v2f xc = __builtin_shufflevector(xb[(h)%3][e], xb[(h)%3][e], 2,3);       \
      f4v A = wrg[(h)%3][2*e], Bv = wrg[(h)%3][2*e+1];                         \
      v2f wa = __builtin_shufflevector(A,A,0,1);                               \
      v2f wb2= __builtin_shufflevector(A,A,2,3);                               \
      v2f wc = __builtin_shufflevector(Bv,Bv,0,1);                             \
      v2f wd = __builtin_shufflevector(Bv,Bv,2,3);                             \
      PKL(acc[0][0],wa,xa);  PKL(acc[0][1],wa,xc);                             \
      PKH(acc[1][0],wa,xa);  PKH(acc[1][1],wa,xc);                             \
      PKL(acc[2][0],wb2,xa); PKL(acc[2][1],wb2,xc);                            \
      PKH(acc[3][0],wb2,xa); PKH(acc[3][1],wb2,xc);                            \
      PKL(acc[4][0],wc,xa);  PKL(acc[4][1],wc,xc);                             \
      PKH(acc[5][0],wc,xa);  PKH(acc[5][1],wc,xc);                             \
      PKL(acc[6][0],wd,xa);  PKL(acc[6][1],wd,xc);                             \
      PKH(acc[7][0],wd,xa);  PKH(acc[7][1],wd,xc);                             \
    } }while(0)

  // one 16-k chunk: barriered LDS fill (verified pattern), then 8 halves
  // pipelined 2 halves deep (3-slot ring, issue after the slot's consumer).
  // Counts: steady-state 18 outstanding before wait; waitl<12> retires
  // exactly half h's 6 reads (in-order) => CH(h) operands ready.
#define CHUNK(pb, t, c) do{                                                    \
    __syncthreads();                                                           \
    _Pragma("unroll")                                                          \
    for (int r=0;r<4;r++)                                                      \
      *(f4v*)&Xs[pb][((tid>>6) + 4*r)*256 + lane*4] = cvt4(sreg[r]);           \
    *(v2f*)&Ws[pb][(wh*4+wg)*16 + 2*we] = wsreg;                               \
    __syncthreads();                                                           \
    { int nch = (t)*NC + (c) + 1; if (nch < T_*NC) ldstage(nch); }             \
    ISSUEH(pb,0); ISSUEH(pb,1); ISSUEH(pb,2);                                  \
    waitl<12>(); CH(0); ISSUEH(pb,3);                                          \
    waitl<12>(); CH(1); ISSUEH(pb,4);                                          \
    waitl<12>(); CH(2); ISSUEH(pb,5);                                          \
    waitl<12>(); CH(3); ISSUEH(pb,6);                                          \
    waitl<12>(); CH(4); ISSUEH(pb,7);                                          \
    waitl<12>(); CH(5);                                                        \
    waitl<6>();  CH(6);                                                        \
    waitl<0>();  CH(7);                                                        \
  }while(0)

  ldstage(0);

  for (int t=0;t<T_;t++){
#pragma unroll
    for (int i=0;i<8;i++){ acc[i][0]=(v2f){0.f,0.f}; acc[i][1]=(v2f){0.f,0.f}; }

#pragma unroll 1
    for (int cc=0; cc<NC; cc+=2){
      CHUNK(0, t, cc);
      CHUNK(1, t, cc+1);
    }

    // epilogue: bias -> BN -> LIF -> store (identical verified formula chain)
#pragma unroll
    for (int i=0;i<8;i++){
      const int o = o0 + wid*8 + i;
      const float g  = bn[o];
      const float be = bn[ODIM + o];
      const float m  = bn[2*ODIM + o];
      const float rs = 1.0f / sqrtf(bn[3*ODIM + o] + 1e-5f);
      const float bi = HAS_BIAS ? bias[o] : 0.0f;
      float sv[4];
#pragma unroll
      for (int jj=0;jj<4;jj++){
        float y  = acc[i][jj>>1][jj&1] + bi;
        float yb = (g*(y - m))*rs + be;
        float vv = vli[i][jj>>1][jj&1];
        vv += (yb - vv)*0.5f;
        float s = (vv >= vth) ? 1.0f : 0.0f;
        vli[i][jj>>1][jj&1] = (s!=0.0f) ? 0.0f : vv;
        sv[jj] = s;
      }
      const size_t base = ((size_t)(t*B_+b)*ODIM + o)*N_ + n0 + 4*lane;
      if (MODE==0){
        u8x4 pa = { (uint8_t)sv[0], (uint8_t)sv[1], (uint8_t)sv[2], (uint8_t)sv[3] };
        *(u8x4*)((uint8_t*)out + base) = pa;
      } else {
        f4v r0 = *(const f4v*)&resid[base];
        f4v w0 = { r0[0]+sv[0], r0[1]+sv[1], r0[2]+sv[2], r0[3]+sv[3] };
        *(f4v*)&((float*)out)[base] = w0;
      }
    }
  }
#undef ISSUEH
#undef CH
#undef CHUNK
}

// kv[t,b,h,d,e] = sum_n k[d,n]*v[e,n] over binary byte spikes (exact popc).
__global__ __launch_bounds__(256)
void kv_kernel(const uint8_t* __restrict__ qkv, float* __restrict__ kvout)
{
  int blk = blockIdx.x;          // (t*B+b)*HEADS + h
  int h = blk & 7, tb = blk >> 3;
  int tid = threadIdx.x;
  int e = tid & 31, d0 = (tid >> 5) * 4;
  const uint8_t* kp = qkv + ((size_t)tb*768 + 256 + h*DH_)*N_;
  const uint8_t* vp = qkv + ((size_t)tb*768 + 512 + h*DH_)*N_;
  const uint4* vr = (const uint4*)(vp + (size_t)e*N_);
  const uint4* k0 = (const uint4*)(kp + (size_t)(d0+0)*N_);
  const uint4* k1 = (const uint4*)(kp + (size_t)(d0+1)*N_);
  const uint4* k2 = (const uint4*)(kp + (size_t)(d0+2)*N_);
  const uint4* k3 = (const uint4*)(kp + (size_t)(d0+3)*N_);
  int s0=0,s1=0,s2=0,s3=0;
  for (int q=0;q<N_/16;q++){
    uint4 vv = vr[q];
    uint4 a0 = k0[q], a1 = k1[q], a2 = k2[q], a3 = k3[q];
    s0 += __popc(a0.x&vv.x)+__popc(a0.y&vv.y)+__popc(a0.z&vv.z)+__popc(a0.w&vv.w);
    s1 += __popc(a1.x&vv.x)+__popc(a1.y&vv.y)+__popc(a1.z&vv.z)+__popc(a1.w&vv.w);
    s2 += __popc(a2.x&vv.x)+__popc(a2.y&vv.y)+__popc(a2.z&vv.z)+__popc(a2.w&vv.w);
    s3 += __popc(a3.x&vv.x)+__popc(a3.y&vv.y)+__popc(a3.z&vv.z)+__popc(a3.w&vv.w);
  }
  float* kvp = kvout + (size_t)blk*DH_*DH_;
  kvp[(d0+0)*DH_ + e] = (float)s0;
  kvp[(d0+1)*DH_ + e] = (float)s1;
  kvp[(d0+2)*DH_ + e] = (float)s2;
  kvp[(d0+3)*DH_ + e] = (float)s3;
}

// a[e,n] = 0.125 * sum_d q[d,n]*kv[d,e]; LIF vth=0.5 (exact dyadic).
__global__ __launch_bounds__(256)
void attn_lif_kernel(const uint8_t* __restrict__ qkv, const float* __restrict__ kv,
                     uint8_t* __restrict__ as_)
{
  int tid = threadIdx.x;
  int n = blockIdx.x*256 + tid;
  int h = blockIdx.y, b = blockIdx.z;
  __shared__ float kvL[DH_*DH_];
  float v[DH_];
#pragma unroll
  for (int e=0;e<DH_;e++) v[e]=0.0f;
  for (int t=0;t<T_;t++){
    const float* kvp = kv + ((size_t)((t*B_+b)*HEADS_+h))*DH_*DH_;
    __syncthreads();
#pragma unroll
    for (int r=0;r<4;r++) kvL[tid+256*r] = kvp[tid+256*r];
    __syncthreads();
    const uint8_t* qp = qkv + ((size_t)(t*B_+b)*768 + h*DH_)*N_ + n;
    float qv[DH_];
#pragma unroll
    for (int d=0;d<DH_;d++) qv[d] = (float)qp[(size_t)d*N_];
    uint8_t* op = as_ + ((size_t)(t*B_+b)*C_ + h*DH_)*N_ + n;
#pragma unroll
    for (int e=0;e<DH_;e++){
      float a=0.0f;
#pragma unroll
      for (int d=0;d<DH_;d++) a += qv[d]*kvL[d*DH_+e];
      a *= 0.125f;
      float vv = v[e];
      vv += (a - vv)*0.5f;
      float s = (vv >= 0.5f) ? 1.0f : 0.0f;
      v[e] = (s!=0.0f) ? 0.0f : vv;
      op[(size_t)e*N_] = (uint8_t)s;
    }
  }
}

extern "C" void kernel_launch(void* const* d_in, const int* in_sizes, int n_in,
                              void* d_out, int out_size, void* d_ws, size_t ws_size,
                              hipStream_t stream)
{
  const float* x      = (const float*)d_in[0];
  const float* wq     = (const float*)d_in[2];
  const float* bn_q   = (const float*)d_in[3];
  const float* wk     = (const float*)d_in[4];
  const float* bn_k   = (const float*)d_in[5];
  const float* wv     = (const float*)d_in[6];
  const float* bn_v   = (const float*)d_in[7];
  const float* wproj  = (const float*)d_in[8];
  const float* bproj  = (const float*)d_in[9];
  const float* bnproj = (const float*)d_in[10];
  const float* wfc1   = (const float*)d_in[11];
  const float* bfc1   = (const float*)d_in[12];
  const float* bnfc1  = (const float*)d_in[13];
  const float* wfc2   = (const float*)d_in[14];
  const float* bfc2   = (const float*)d_in[15];
  const float* bnfc2  = (const float*)d_in[16];

  char* ws = (char*)d_ws;
  const size_t TB = (size_t)T_*B_;
  uint8_t* qkv = (uint8_t*)ws;                       // TB*768*N
  uint8_t* as_ = (uint8_t*)ws + TB*768*N_;           // TB*256*N
  uint8_t* h1s = (uint8_t*)ws;                       // TB*1024*N (overlay)
  size_t off = TB*768*N_ + TB*(size_t)C_*N_;
  float* xnew = (float*)(ws + off); off += TB*(size_t)C_*N_*4;
  float* WpQ  = (float*)(ws + off); off += (size_t)C_*768*4;
  float* WpP  = (float*)(ws + off); off += (size_t)C_*C_*4;
  float* WpF1 = (float*)(ws + off); off += (size_t)C_*HD_*4;
  float* WpF2 = (float*)(ws + off); off += (size_t)HD_*C_*4;
  float* bnQ  = (float*)(ws + off); off += 4*768*4;
  float* kvb  = (float*)(ws + off); off += TB*HEADS_*DH_*DH_*4;

  dim3 blk(256);
  packW<<<dim3(1,256),blk,0,stream>>>(wq,    WpQ,  256,  768,   0);
  packW<<<dim3(1,256),blk,0,stream>>>(wk,    WpQ,  256,  768, 256);
  packW<<<dim3(1,256),blk,0,stream>>>(wv,    WpQ,  256,  768, 512);
  packW<<<dim3(1,256),blk,0,stream>>>(wproj, WpP,  256,  256,   0);
  packW<<<dim3(1,1024),blk,0,stream>>>(wfc1, WpF1, 256, 1024,   0);
  packW<<<dim3(4,256),blk,0,stream>>>(wfc2,  WpF2, 1024, 256,   0);
  packBn3<<<dim3(4),blk,0,stream>>>(bn_q, bn_k, bn_v, bnQ);

  // fused QKV GEMM -> spikes
  dgemm<C_,768,false,0,float><<<dim3(4,24,16),blk,0,stream>>>(
      x, WpQ, nullptr, bnQ, nullptr, qkv, 1.0f);
  kv_kernel<<<dim3(T_*B_*HEADS_),blk,0,stream>>>(qkv, kvb);
  attn_lif_kernel<<<dim3(4,HEADS_,B_),blk,0,stream>>>(qkv, kvb, as_);
  // proj -> xnew = x + attn spike
  dgemm<C_,C_,true,1,uint8_t><<<dim3(4,8,16),blk,0,stream>>>(
      as_, WpP, bproj, bnproj, x, xnew, 1.0f);
  // fc1 -> h1 spikes (overlays dead qkv/as_)
  dgemm<C_,HD_,true,0,float><<<dim3(4,32,16),blk,0,stream>>>(
      xnew, WpF1, bfc1, bnfc1, nullptr, h1s, 1.0f);
  // fc2 -> out = xnew + mlp spike
  dgemm<HD_,C_,true,1,uint8_t><<<dim3(4,8,16),blk,0,stream>>>(
      h1s, WpF2, bfc2, bnfc2, xnew, d_out, 1.0f);
}

// Round 12
// 1463.776 us; speedup vs baseline: 1.0180x; 1.0180x over previous
//
#include <hip/hip_runtime.h>
#include <stdint.h>
#include <math.h>

#define T_ 4
#define B_ 16
#define C_ 256
#define N_ 1024
#define HD_ 1024
#define HEADS_ 8
#define DH_ 32

typedef float   v2f  __attribute__((ext_vector_type(2)));
typedef float   f4v  __attribute__((ext_vector_type(4)));
typedef uint8_t u8x4 __attribute__((ext_vector_type(4)));

// v_pk_fma_f32 with op_sel broadcasting one 32-bit half of src0 (VGPR) to both
// halves. Two independent IEEE fp32 FMAs; bit-exact per-output chains.
// (Verified numerically correct: rounds 0/6/10/11, absmax 0.0.)
#define PKL(a, w, x) asm volatile("v_pk_fma_f32 %0, %1, %2, %0 op_sel:[0,0,0] op_sel_hi:[0,1,1]" : "+v"(a) : "v"(w), "v"(x))
#define PKH(a, w, x) asm volatile("v_pk_fma_f32 %0, %1, %2, %0 op_sel:[1,0,0] op_sel_hi:[1,1,1]" : "+v"(a) : "v"(w), "v"(x))

// counted lgkm wait: SAFE because the counted region contains ONLY DS ops
// (ds_* retire in-order in lgkmcnt; no SMEM/flat in the counted region —
// ldstage forced to address_space(1) => global_load => vmcnt only).
template<int N> __device__ __forceinline__ void waitl(){
  asm volatile("s_waitcnt lgkmcnt(%0)" :: "i"(N) : "memory");
  __builtin_amdgcn_sched_barrier(0);       // rule #18 fence
}

// Wp[((k>>1)*(OD/8) + (o+ooff)/8)*16 + (k&1)*8 + (o+ooff)%8] = W[o][k]
// => contiguous 64B per {2 k's} x {8 o's} half-tile.
__global__ __launch_bounds__(256)
void packW(const float* __restrict__ W, float* __restrict__ Wp,
           int K, int OD, int ooff)
{
  int k = blockIdx.x*256 + threadIdx.x;
  int oo = blockIdx.y + ooff;
  Wp[((size_t)(k>>1)*(OD>>3) + (oo>>3))*16 + ((k&1)<<3) + (oo&7)]
      = W[(size_t)blockIdx.y*K + k];
}

__global__ __launch_bounds__(256)
void packBn3(const float* __restrict__ a, const float* __restrict__ b,
             const float* __restrict__ c, float* __restrict__ o)
{
  int i = blockIdx.x*256 + threadIdx.x;            // 0..1023 = [4][256]
  int r = i >> 8, ci = i & 255;
  o[(size_t)r*768 + ci]       = a[i];
  o[(size_t)r*768 + 256 + ci] = b[i];
  o[(size_t)r*768 + 512 + ci] = c[i];
}

template<typename T> struct VecT;
template<> struct VecT<float>  { using t = f4v;  };
template<> struct VecT<uint8_t>{ using t = u8x4; };
__device__ __forceinline__ f4v cvt4(f4v v){ return v; }
__device__ __forceinline__ f4v cvt4(u8x4 u){
  return (f4v){ (float)u[0], (float)u[1], (float)u[2], (float)u[3] };
}

// ---------------------------------------------------------------------------
// Y = W @ X (+bias) -> BN -> LIF, t-loop inside block (LIF state in regs).
// Block 256 thr: o-tile 32 (wave owns 8 o, wave-uniform), n-tile 256 (lane 4n).
// BOTH X and W staged global->reg->LDS per 16-k chunk (verified pattern);
// hot loop is PURE DS: per half (2 k's) 2 contiguous ds_read_b128 (X) + 4
// wave-uniform broadcast ds_read_b128 (W, conflict-free).
// 3-slot register ring, issue-ahead distance 2 halves (~128cy > ~120cy LDS
// latency).  Counted lgkmcnt exact (in-order DS).
// launch_bounds (256,2): round-11 PMC showed (256,3) pinned VGPR at 84 and
// spilled the ring to scratch (+48MB/dispatch HBM traffic) — relaxed cap
// removes the spills; LDS (36KB -> 4 blocks/CU) still bounds occupancy.
// Numeric contract: per output, strictly k-ascending fp32 FMA chain;
// epilogue formula chain identical to all verified rounds (absmax 0.0).
// ---------------------------------------------------------------------------
template<int KDIM,int ODIM,bool HAS_BIAS,int MODE,typename TIn>
__global__ __launch_bounds__(256,2)
void dgemm(const TIn* __restrict__ X, const float* __restrict__ Wp,
           const float* __restrict__ bias, const float* __restrict__ bn,
           const float* __restrict__ resid, void* __restrict__ out, float vth)
{
  using XV = typename VecT<TIn>::t;
  constexpr int NC = KDIM/16;                 // 16-k chunks per t
  __shared__ __align__(16) float Xs[2][16*256];   // 32 KB
  __shared__ __align__(16) float Ws[2][512];      //  4 KB

  const int tid  = threadIdx.x;
  const int lane = tid & 63;
  const int wid  = __builtin_amdgcn_readfirstlane(tid >> 6);
  const int b    = blockIdx.z, n0 = blockIdx.x*256, o0 = blockIdx.y*32;
  const int og0  = o0 >> 3;
  // W-stage decomposition of tid: half wh (0..7), o-group wg (0..3), elem we
  const int wh = tid >> 5, wg = (tid >> 3) & 3, we = tid & 7;

  const uint32_t lxB =
      (uint32_t)(uintptr_t)(__attribute__((address_space(3))) float*)&Xs[0][0]
      + (uint32_t)(lane*16);
  const uint32_t lwB =
      (uint32_t)(uintptr_t)(__attribute__((address_space(3))) float*)&Ws[0][0]
      + (uint32_t)(wid*64);

  v2f acc[8][2], vli[8][2];
#pragma unroll
  for (int i=0;i<8;i++){ vli[i][0]=(v2f){0.f,0.f}; vli[i][1]=(v2f){0.f,0.f}; }

  f4v xb[3][2];      // [h mod 3][k-parity]
  f4v wrg[3][4];     // [h mod 3][{kev o0-3, kev o4-7, kod o0-3, kod o4-7}]
  XV  sreg[4];
  v2f wsreg;

  // stage-register loads for global chunk ch = t*NC + c.
  // Explicit address_space(1) => global_load (vmcnt ONLY — never flat/lgkm),
  // keeping the counted-lgkm region pure-DS.  Issued a full chunk (~1000cy)
  // ahead of the LDS write => covers HBM latency.
  auto ldstage = [&](int ch){
    const int t = ch / NC, c = ch % NC;
    const TIn* Xg = X + ((size_t)(t*B_+b)*KDIM + c*16)*N_ + n0 + lane*4;
#pragma unroll
    for (int r=0;r<4;r++)
      sreg[r] = *(const __attribute__((address_space(1))) XV*)
                  (Xg + (size_t)((tid>>6) + 4*r)*N_);
    wsreg = *(const __attribute__((address_space(1))) v2f*)
        (Wp + ((size_t)(c*8 + wh)*(ODIM>>3) + og0 + wg)*16 + 2*we);
  };

  // issue all 6 DS reads for half h of buffer pb (pb,h compile-time literals)
#define ISSUEH(pb, h) do{                                                      \
    uint32_t lx_ = lxB + (uint32_t)((pb)*16384 + (h)*2048);                    \
    asm volatile("ds_read_b128 %0, %2\n\tds_read_b128 %1, %2 offset:1024"      \
                 : "=v"(xb[(h)%3][0]), "=v"(xb[(h)%3][1]) : "v"(lx_));         \
    uint32_t lw_ = lwB + (uint32_t)((pb)*2048 + (h)*256);                      \
    asm volatile("ds_read_b128 %0, %4\n\tds_read_b128 %1, %4 offset:16\n\t"    \
                 "ds_read_b128 %2, %4 offset:32\n\tds_read_b128 %3, %4 offset:48" \
                 : "=v"(wrg[(h)%3][0]), "=v"(wrg[(h)%3][1]),                   \
                   "=v"(wrg[(h)%3][2]), "=v"(wrg[(h)%3][3]) : "v"(lw_));       \
  }while(0)

  // compute half h: k=2h then k=2h+1; strict ascending-k order per output
#define CH(h) do{                                                              \
    _Pragma("unroll")                                                          \
    for (int e=0;e<2;e++){                                                     \
      v2f xa = __builtin_shufflevector(xb[(h)%3][e], xb[(h)%3][e], 0,1);       \
      v2f xc = __builtin_shufflevector(xb[(h)%3][e], xb[(h)%3][e], 2,3);       \
      f4v A = wrg[(h)%3][2*e], Bv = wrg[(h)%3][2*e+1];                         \
      v2f wa = __builtin_shufflevector(A,A,0,1);                               \
      v2f wb2= __builtin_shufflevector(A,A,2,3);                               \
      v2f wc = __builtin_shufflevector(Bv,Bv,0,1);                             \
      v2f wd = __builtin_shufflevector(Bv,Bv,2,3);                             \
      PKL(acc[0][0],wa,xa);  PKL(acc[0][1],wa,xc);                             \
      PKH(acc[1][0],wa,xa);  PKH(acc[1][1],wa,xc);                             \
      PKL(acc[2][0],wb2,xa); PKL(acc[2][1],wb2,xc);                            \
      PKH(acc[3][0],wb2,xa); PKH(acc[3][1],wb2,xc);                            \
      PKL(acc[4][0],wc,xa);  PKL(acc[4][1],wc,xc);                             \
      PKH(acc[5][0],wc,xa);  PKH(acc[5][1],wc,xc);                             \
      PKL(acc[6][0],wd,xa);  PKL(acc[6][1],wd,xc);                             \
      PKH(acc[7][0],wd,xa);  PKH(acc[7][1],wd,xc);                             \
    } }while(0)

  // one 16-k chunk: barriered LDS fill (verified pattern), then 8 halves
  // pipelined 2 halves deep (3-slot ring, issue after the slot's consumer).
  // Counts: steady-state 18 outstanding before wait; waitl<12> retires
  // exactly half h's 6 reads (in-order) => CH(h) operands ready.
#define CHUNK(pb, t, c) do{                                                    \
    __syncthreads();                                                           \
    _Pragma("unroll")                                                          \
    for (int r=0;r<4;r++)                                                      \
      *(f4v*)&Xs[pb][((tid>>6) + 4*r)*256 + lane*4] = cvt4(sreg[r]);           \
    *(v2f*)&Ws[pb][(wh*4+wg)*16 + 2*we] = wsreg;                               \
    __syncthreads();                                                           \
    { int nch = (t)*NC + (c) + 1; if (nch < T_*NC) ldstage(nch); }             \
    ISSUEH(pb,0); ISSUEH(pb,1); ISSUEH(pb,2);                                  \
    waitl<12>(); CH(0); ISSUEH(pb,3);                                          \
    waitl<12>(); CH(1); ISSUEH(pb,4);                                          \
    waitl<12>(); CH(2); ISSUEH(pb,5);                                          \
    waitl<12>(); CH(3); ISSUEH(pb,6);                                          \
    waitl<12>(); CH(4); ISSUEH(pb,7);                                          \
    waitl<12>(); CH(5);                                                        \
    waitl<6>();  CH(6);                                                        \
    waitl<0>();  CH(7);                                                        \
  }while(0)

  ldstage(0);

  for (int t=0;t<T_;t++){
#pragma unroll
    for (int i=0;i<8;i++){ acc[i][0]=(v2f){0.f,0.f}; acc[i][1]=(v2f){0.f,0.f}; }

#pragma unroll 1
    for (int cc=0; cc<NC; cc+=2){
      CHUNK(0, t, cc);
      CHUNK(1, t, cc+1);
    }

    // epilogue: bias -> BN -> LIF -> store (identical verified formula chain)
#pragma unroll
    for (int i=0;i<8;i++){
      const int o = o0 + wid*8 + i;
      const float g  = bn[o];
      const float be = bn[ODIM + o];
      const float m  = bn[2*ODIM + o];
      const float rs = 1.0f / sqrtf(bn[3*ODIM + o] + 1e-5f);
      const float bi = HAS_BIAS ? bias[o] : 0.0f;
      float sv[4];
#pragma unroll
      for (int jj=0;jj<4;jj++){
        float y  = acc[i][jj>>1][jj&1] + bi;
        float yb = (g*(y - m))*rs + be;
        float vv = vli[i][jj>>1][jj&1];
        vv += (yb - vv)*0.5f;
        float s = (vv >= vth) ? 1.0f : 0.0f;
        vli[i][jj>>1][jj&1] = (s!=0.0f) ? 0.0f : vv;
        sv[jj] = s;
      }
      const size_t base = ((size_t)(t*B_+b)*ODIM + o)*N_ + n0 + 4*lane;
      if (MODE==0){
        u8x4 pa = { (uint8_t)sv[0], (uint8_t)sv[1], (uint8_t)sv[2], (uint8_t)sv[3] };
        *(u8x4*)((uint8_t*)out + base) = pa;
      } else {
        f4v r0 = *(const f4v*)&resid[base];
        f4v w0 = { r0[0]+sv[0], r0[1]+sv[1], r0[2]+sv[2], r0[3]+sv[3] };
        *(f4v*)&((float*)out)[base] = w0;
      }
    }
  }
#undef ISSUEH
#undef CH
#undef CHUNK
}

// kv[t,b,h,d,e] = sum_n k[d,n]*v[e,n] over binary byte spikes (exact popc).
__global__ __launch_bounds__(256)
void kv_kernel(const uint8_t* __restrict__ qkv, float* __restrict__ kvout)
{
  int blk = blockIdx.x;          // (t*B+b)*HEADS + h
  int h = blk & 7, tb = blk >> 3;
  int tid = threadIdx.x;
  int e = tid & 31, d0 = (tid >> 5) * 4;
  const uint8_t* kp = qkv + ((size_t)tb*768 + 256 + h*DH_)*N_;
  const uint8_t* vp = qkv + ((size_t)tb*768 + 512 + h*DH_)*N_;
  const uint4* vr = (const uint4*)(vp + (size_t)e*N_);
  const uint4* k0 = (const uint4*)(kp + (size_t)(d0+0)*N_);
  const uint4* k1 = (const uint4*)(kp + (size_t)(d0+1)*N_);
  const uint4* k2 = (const uint4*)(kp + (size_t)(d0+2)*N_);
  const uint4* k3 = (const uint4*)(kp + (size_t)(d0+3)*N_);
  int s0=0,s1=0,s2=0,s3=0;
  for (int q=0;q<N_/16;q++){
    uint4 vv = vr[q];
    uint4 a0 = k0[q], a1 = k1[q], a2 = k2[q], a3 = k3[q];
    s0 += __popc(a0.x&vv.x)+__popc(a0.y&vv.y)+__popc(a0.z&vv.z)+__popc(a0.w&vv.w);
    s1 += __popc(a1.x&vv.x)+__popc(a1.y&vv.y)+__popc(a1.z&vv.z)+__popc(a1.w&vv.w);
    s2 += __popc(a2.x&vv.x)+__popc(a2.y&vv.y)+__popc(a2.z&vv.z)+__popc(a2.w&vv.w);
    s3 += __popc(a3.x&vv.x)+__popc(a3.y&vv.y)+__popc(a3.z&vv.z)+__popc(a3.w&vv.w);
  }
  float* kvp = kvout + (size_t)blk*DH_*DH_;
  kvp[(d0+0)*DH_ + e] = (float)s0;
  kvp[(d0+1)*DH_ + e] = (float)s1;
  kvp[(d0+2)*DH_ + e] = (float)s2;
  kvp[(d0+3)*DH_ + e] = (float)s3;
}

// a[e,n] = 0.125 * sum_d q[d,n]*kv[d,e]; LIF vth=0.5 (exact dyadic).
__global__ __launch_bounds__(256)
void attn_lif_kernel(const uint8_t* __restrict__ qkv, const float* __restrict__ kv,
                     uint8_t* __restrict__ as_)
{
  int tid = threadIdx.x;
  int n = blockIdx.x*256 + tid;
  int h = blockIdx.y, b = blockIdx.z;
  __shared__ float kvL[DH_*DH_];
  float v[DH_];
#pragma unroll
  for (int e=0;e<DH_;e++) v[e]=0.0f;
  for (int t=0;t<T_;t++){
    const float* kvp = kv + ((size_t)((t*B_+b)*HEADS_+h))*DH_*DH_;
    __syncthreads();
#pragma unroll
    for (int r=0;r<4;r++) kvL[tid+256*r] = kvp[tid+256*r];
    __syncthreads();
    const uint8_t* qp = qkv + ((size_t)(t*B_+b)*768 + h*DH_)*N_ + n;
    float qv[DH_];
#pragma unroll
    for (int d=0;d<DH_;d++) qv[d] = (float)qp[(size_t)d*N_];
    uint8_t* op = as_ + ((size_t)(t*B_+b)*C_ + h*DH_)*N_ + n;
#pragma unroll
    for (int e=0;e<DH_;e++){
      float a=0.0f;
#pragma unroll
      for (int d=0;d<DH_;d++) a += qv[d]*kvL[d*DH_+e];
      a *= 0.125f;
      float vv = v[e];
      vv += (a - vv)*0.5f;
      float s = (vv >= 0.5f) ? 1.0f : 0.0f;
      v[e] = (s!=0.0f) ? 0.0f : vv;
      op[(size_t)e*N_] = (uint8_t)s;
    }
  }
}

extern "C" void kernel_launch(void* const* d_in, const int* in_sizes, int n_in,
                              void* d_out, int out_size, void* d_ws, size_t ws_size,
                              hipStream_t stream)
{
  const float* x      = (const float*)d_in[0];
  const float* wq     = (const float*)d_in[2];
  const float* bn_q   = (const float*)d_in[3];
  const float* wk     = (const float*)d_in[4];
  const float* bn_k   = (const float*)d_in[5];
  const float* wv     = (const float*)d_in[6];
  const float* bn_v   = (const float*)d_in[7];
  const float* wproj  = (const float*)d_in[8];
  const float* bproj  = (const float*)d_in[9];
  const float* bnproj = (const float*)d_in[10];
  const float* wfc1   = (const float*)d_in[11];
  const float* bfc1   = (const float*)d_in[12];
  const float* bnfc1  = (const float*)d_in[13];
  const float* wfc2   = (const float*)d_in[14];
  const float* bfc2   = (const float*)d_in[15];
  const float* bnfc2  = (const float*)d_in[16];

  char* ws = (char*)d_ws;
  const size_t TB = (size_t)T_*B_;
  uint8_t* qkv = (uint8_t*)ws;                       // TB*768*N
  uint8_t* as_ = (uint8_t*)ws + TB*768*N_;           // TB*256*N
  uint8_t* h1s = (uint8_t*)ws;                       // TB*1024*N (overlay)
  size_t off = TB*768*N_ + TB*(size_t)C_*N_;
  float* xnew = (float*)(ws + off); off += TB*(size_t)C_*N_*4;
  float* WpQ  = (float*)(ws + off); off += (size_t)C_*768*4;
  float* WpP  = (float*)(ws + off); off += (size_t)C_*C_*4;
  float* WpF1 = (float*)(ws + off); off += (size_t)C_*HD_*4;
  float* WpF2 = (float*)(ws + off); off += (size_t)HD_*C_*4;
  float* bnQ  = (float*)(ws + off); off += 4*768*4;
  float* kvb  = (float*)(ws + off); off += TB*HEADS_*DH_*DH_*4;

  dim3 blk(256);
  packW<<<dim3(1,256),blk,0,stream>>>(wq,    WpQ,  256,  768,   0);
  packW<<<dim3(1,256),blk,0,stream>>>(wk,    WpQ,  256,  768, 256);
  packW<<<dim3(1,256),blk,0,stream>>>(wv,    WpQ,  256,  768, 512);
  packW<<<dim3(1,256),blk,0,stream>>>(wproj, WpP,  256,  256,   0);
  packW<<<dim3(1,1024),blk,0,stream>>>(wfc1, WpF1, 256, 1024,   0);
  packW<<<dim3(4,256),blk,0,stream>>>(wfc2,  WpF2, 1024, 256,   0);
  packBn3<<<dim3(4),blk,0,stream>>>(bn_q, bn_k, bn_v, bnQ);

  // fused QKV GEMM -> spikes
  dgemm<C_,768,false,0,float><<<dim3(4,24,16),blk,0,stream>>>(
      x, WpQ, nullptr, bnQ, nullptr, qkv, 1.0f);
  kv_kernel<<<dim3(T_*B_*HEADS_),blk,0,stream>>>(qkv, kvb);
  attn_lif_kernel<<<dim3(4,HEADS_,B_),blk,0,stream>>>(qkv, kvb, as_);
  // proj -> xnew = x + attn spike
  dgemm<C_,C_,true,1,uint8_t><<<dim3(4,8,16),blk,0,stream>>>(
      as_, WpP, bproj, bnproj, x, xnew, 1.0f);
  // fc1 -> h1 spikes (overlays dead qkv/as_)
  dgemm<C_,HD_,true,0,float><<<dim3(4,32,16),blk,0,stream>>>(
      xnew, WpF1, bfc1, bnfc1, nullptr, h1s, 1.0f);
  // fc2 -> out = xnew + mlp spike
  dgemm<HD_,C_,true,1,uint8_t><<<dim3(4,8,16),blk,0,stream>>>(
      h1s, WpF2, bfc2, bnfc2, xnew, d_out, 1.0f);
}